// Round 14
// baseline (414.642 us; speedup 1.0000x reference)
//
#include <hip/hip_runtime.h>

typedef __attribute__((ext_vector_type(8))) short bf16x8;
typedef __attribute__((ext_vector_type(4))) float f32x4;
typedef unsigned short u16;

#define AS1 __attribute__((address_space(1)))
#define AS3 __attribute__((address_space(3)))

__device__ __forceinline__ u16 f2bf(float f) {
    union { float f; unsigned u; } v; v.f = f;
    unsigned u = v.u;
    return (u16)((u + 0x7FFFu + ((u >> 16) & 1u)) >> 16);
}
__device__ __forceinline__ float bf2f(u16 h) {
    union { unsigned u; float f; } v; v.u = ((unsigned)h) << 16;
    return v.f;
}

// ---- zero deg
__global__ __launch_bounds__(256) void k_zero(int4* __restrict__ p, int n4) {
    int i = blockIdx.x * 256 + threadIdx.x;
    if (i < n4) p[i] = make_int4(0, 0, 0, 0);
}

// ---- fused fp32->bf16 convert (x -> hb) + degree count
__global__ __launch_bounds__(256) void k_convcnt(const float* __restrict__ x,
                                                 u16* __restrict__ hb, int total4,
                                                 const int* __restrict__ dst,
                                                 int* __restrict__ deg, int E) {
    int i = blockIdx.x * 256 + threadIdx.x;
    if (i < total4) {
        float4 v = ((const float4*)x)[i];
        ushort4 o;
        o.x = f2bf(v.x); o.y = f2bf(v.y); o.z = f2bf(v.z); o.w = f2bf(v.w);
        ((ushort4*)hb)[i] = o;
    }
    if (i < E) atomicAdd(&deg[dst[i]], 1);
}

// ---- hierarchical exclusive scan of deg -> rp, cur ----
__global__ __launch_bounds__(256) void k_part(const int* __restrict__ deg,
                                              int* __restrict__ part, int N) {
    __shared__ int ws[4];
    int i = blockIdx.x * 256 + threadIdx.x;
    int v = (i < N) ? deg[i] : 0;
#pragma unroll
    for (int o = 32; o; o >>= 1) v += __shfl_down(v, o);
    int lane = threadIdx.x & 63, w = threadIdx.x >> 6;
    if (lane == 0) ws[w] = v;
    __syncthreads();
    if (threadIdx.x == 0) part[blockIdx.x] = ws[0] + ws[1] + ws[2] + ws[3];
}

__global__ __launch_bounds__(256) void k_scanp(const int* __restrict__ part,
                                               int* __restrict__ bases, int P) {
    __shared__ int s[256];
    int t = threadIdx.x;
    int v = (t < P) ? part[t] : 0;
    s[t] = v;
    __syncthreads();
#pragma unroll
    for (int o = 1; o < 256; o <<= 1) {
        int u = (t >= o) ? s[t - o] : 0;
        __syncthreads();
        s[t] += u;
        __syncthreads();
    }
    bases[t] = s[t] - v;  // exclusive
}

__global__ __launch_bounds__(256) void k_apply(const int* __restrict__ deg,
                                               const int* __restrict__ bases,
                                               int* __restrict__ rp, int* __restrict__ cur,
                                               int N, int E) {
    __shared__ int s[256];
    int b = blockIdx.x, t = threadIdx.x;
    int i = b * 256 + t;
    int d = (i < N) ? deg[i] : 0;
    s[t] = d;
    __syncthreads();
#pragma unroll
    for (int o = 1; o < 256; o <<= 1) {
        int u = (t >= o) ? s[t - o] : 0;
        __syncthreads();
        s[t] += u;
        __syncthreads();
    }
    if (i < N) {
        int r = bases[b] + s[t] - d;
        rp[i] = r;
        cur[i] = r;
    }
    if (b == (int)gridDim.x - 1 && t == 255) rp[N] = E;
}

__global__ __launch_bounds__(256) void k_fill(const int* __restrict__ dst, const int* __restrict__ src,
                                              int* __restrict__ cur,
                                              int* __restrict__ eid, int* __restrict__ srcs, int E) {
    int e = blockIdx.x * 256 + threadIdx.x;
    if (e < E) {
        int p = atomicAdd(&cur[dst[e]], 1);
        eid[p] = e;
        srcs[p] = src[e];
    }
}

// Sa[v][k] = inv_deg * sum_{e->v} attr[e][k]  (bf16), hasdeg[v]
__global__ __launch_bounds__(256) void k_sa(const float* __restrict__ attr, const int* __restrict__ rp,
                                            const int* __restrict__ eid, u16* __restrict__ Sa,
                                            unsigned char* __restrict__ hasdeg, int N) {
    int v = blockIdx.x * 4 + (threadIdx.x >> 6);
    if (v >= N) return;
    int l = threadIdx.x & 63;
    int g = l >> 4;          // edge subgroup 0..3
    int c = (l & 15) * 4;    // col base
    int j0 = rp[v], j1 = rp[v + 1];
    float4 a = {0.f, 0.f, 0.f, 0.f};
    int jc = j1 - 1;
    for (int j = j0; j < j1; j += 8) {
        int i0 = j + g;
        int i1 = j + 4 + g;
        float m0 = (i0 < j1) ? 1.f : 0.f;
        float m1 = (i1 < j1) ? 1.f : 0.f;
        int e0 = eid[i0 < jc ? i0 : jc];
        int e1 = eid[i1 < jc ? i1 : jc];
        float4 x0 = *(const float4*)&attr[(size_t)e0 * 64 + c];
        float4 x1 = *(const float4*)&attr[(size_t)e1 * 64 + c];
        a.x += m0 * x0.x + m1 * x1.x;
        a.y += m0 * x0.y + m1 * x1.y;
        a.z += m0 * x0.z + m1 * x1.z;
        a.w += m0 * x0.w + m1 * x1.w;
    }
    a.x += __shfl_xor(a.x, 16); a.y += __shfl_xor(a.y, 16);
    a.z += __shfl_xor(a.z, 16); a.w += __shfl_xor(a.w, 16);
    a.x += __shfl_xor(a.x, 32); a.y += __shfl_xor(a.y, 32);
    a.z += __shfl_xor(a.z, 32); a.w += __shfl_xor(a.w, 32);
    int dg = j1 - j0;
    float m = 1.f / (float)(dg > 1 ? dg : 1);
    if (l < 16) {
        ushort4 o;
        o.x = f2bf(a.x * m); o.y = f2bf(a.y * m);
        o.z = f2bf(a.z * m); o.w = f2bf(a.w * m);
        *(ushort4*)&Sa[(size_t)v * 64 + c] = o;
        if (l == 0) hasdeg[v] = (dg > 0) ? 1 : 0;
    }
}

// Sx[v][:] = inv_deg * sum_{e->v} h[src_e][:]  (bf16 in, fp32 accum, bf16 out)
__global__ __launch_bounds__(256) void k_sx(const u16* __restrict__ hb, const int* __restrict__ rp,
                                            const int* __restrict__ srcs,
                                            u16* __restrict__ Sx, int N) {
    int v = blockIdx.x * 4 + (threadIdx.x >> 6);
    if (v >= N) return;
    int l = threadIdx.x & 63;
    int h = l >> 5;           // row subgroup 0/1
    int c = (l & 31) * 8;     // col base (bf16)
    int j0 = rp[v], j1 = rp[v + 1];
    float a[8] = {0.f, 0.f, 0.f, 0.f, 0.f, 0.f, 0.f, 0.f};
    int jc = j1 - 1;
    for (int j = j0; j < j1; j += 8) {
        int i0 = j + h;
        int i1 = j + 2 + h;
        int i2 = j + 4 + h;
        int i3 = j + 6 + h;
        float m0 = (i0 < j1) ? 1.f : 0.f;
        float m1 = (i1 < j1) ? 1.f : 0.f;
        float m2 = (i2 < j1) ? 1.f : 0.f;
        float m3 = (i3 < j1) ? 1.f : 0.f;
        int s0 = srcs[i0 < jc ? i0 : jc];
        int s1 = srcs[i1 < jc ? i1 : jc];
        int s2 = srcs[i2 < jc ? i2 : jc];
        int s3 = srcs[i3 < jc ? i3 : jc];
        bf16x8 u0 = *(const bf16x8*)&hb[(size_t)s0 * 256 + c];
        bf16x8 u1 = *(const bf16x8*)&hb[(size_t)s1 * 256 + c];
        bf16x8 u2 = *(const bf16x8*)&hb[(size_t)s2 * 256 + c];
        bf16x8 u3 = *(const bf16x8*)&hb[(size_t)s3 * 256 + c];
#pragma unroll
        for (int i = 0; i < 8; ++i)
            a[i] += (m0 * bf2f((u16)u0[i]) + m1 * bf2f((u16)u1[i]))
                  + (m2 * bf2f((u16)u2[i]) + m3 * bf2f((u16)u3[i]));
    }
#pragma unroll
    for (int i = 0; i < 8; ++i) a[i] += __shfl_xor(a[i], 32);
    int dg = j1 - j0;
    float m = 1.f / (float)(dg > 1 ? dg : 1);
    if (l < 32) {
        bf16x8 o;
#pragma unroll
        for (int i = 0; i < 8; ++i) o[i] = (short)f2bf(a[i] * m);
        *(bf16x8*)&Sx[(size_t)v * 256 + c] = o;
    }
}

// fused weight prep: Wl/Wr -> bf16; Wle = Wl@We -> bf16; wlbe = Wl@be
__global__ __launch_bounds__(256) void k_wprep(const float* __restrict__ Wl, const float* __restrict__ Wr,
                                               const float* __restrict__ We, const float* __restrict__ be,
                                               u16* __restrict__ Wlb, u16* __restrict__ Wrb,
                                               u16* __restrict__ Wleb, float* __restrict__ wlbe) {
    int t = blockIdx.x * 256 + threadIdx.x;
    if (t < 3 * 65536) { Wlb[t] = f2bf(Wl[t]); Wrb[t] = f2bf(Wr[t]); }
    if (t < 3 * 16384) {
        int l = t >> 14;
        int r = t & 16383;
        int d = r >> 6, jj = r & 63;
        const float* wl = Wl + ((size_t)l << 16) + (size_t)d * 256;
        const float* we = We + ((size_t)l << 14) + jj;
        float s = 0.f;
        for (int p = 0; p < 256; ++p) s += wl[p] * we[(size_t)p * 64];
        Wleb[t] = f2bf(s);
    }
    if (t < 768) {
        int l = t >> 8, d = t & 255;
        const float* wl = Wl + ((size_t)l << 16) + (size_t)d * 256;
        const float* b = be + l * 256;
        float s = 0.f;
        for (int p = 0; p < 256; ++p) s += wl[p] * b[p];
        wlbe[t] = s;
    }
}

// ---- m97-template GEMM segment with T2 both-sides XOR chunk-swizzle.
// Row = 128B = 8 chunks of 16B. LDS[row][chunk] holds global chunk (chunk^(row&7)):
// staging lane (row=lane>>3, chunk=lane&7) loads global chunk (lane&7)^(lane>>3);
// ds_read of (row, chunk) uses chunk^(row&7). Involution -> bijective (rule #21).
__device__ __forceinline__ void do_seg(const u16* __restrict__ A, const u16* __restrict__ B,
                                       int lda, int K, int r0, int c0, int M,
                                       u16* Alds, u16* Blds,
                                       int lane, int w, int wr, int wc,
                                       int r16, f32x4 (&acc)[4][4]) {
    const int rloc = lane >> 3;                    // 0..7 row within 8-row chunk
    const int cSw = (((lane & 7) ^ rloc) * 8);     // swizzled source chunk (elems)
    const int hi = (lane >> 4) & 3;                // 0..3 k-quad
    for (int k0 = 0; k0 < K; k0 += 64) {
        __syncthreads();   // protect LDS from previous k-step's readers
#pragma unroll
        for (int i = 0; i < 4; ++i) {
            int ch = w * 4 + i;                       // chunk 0..15 (8 rows each)
            int ar = r0 + ch * 8 + rloc;
            ar = ar < M ? ar : M - 1;                 // clamp (dup rows, masked at store)
            __builtin_amdgcn_global_load_lds(
                (const AS1 void*)(A + (size_t)ar * lda + k0 + cSw),
                (AS3 void*)(Alds + ch * 512), 16, 0, 0);
            int br = c0 + ch * 8 + rloc;
            __builtin_amdgcn_global_load_lds(
                (const AS1 void*)(B + (size_t)br * K + k0 + cSw),
                (AS3 void*)(Blds + ch * 512), 16, 0, 0);
        }
        __syncthreads();   // staged data visible
        bf16x8 af[4][2], bfr[4][2];
#pragma unroll
        for (int rf = 0; rf < 4; ++rf) {
            int row = wr * 64 + rf * 16 + r16;
            af[rf][0] = *(const bf16x8*)&Alds[row * 64 + ((hi ^ (row & 7)) * 8)];
            af[rf][1] = *(const bf16x8*)&Alds[row * 64 + (((hi + 4) ^ (row & 7)) * 8)];
        }
#pragma unroll
        for (int cf = 0; cf < 4; ++cf) {
            int row = wc * 64 + cf * 16 + r16;
            bfr[cf][0] = *(const bf16x8*)&Blds[row * 64 + ((hi ^ (row & 7)) * 8)];
            bfr[cf][1] = *(const bf16x8*)&Blds[row * 64 + (((hi + 4) ^ (row & 7)) * 8)];
        }
        __builtin_amdgcn_s_setprio(1);   // T5: favor MFMA cluster vs other blocks' staging
#pragma unroll
        for (int rf = 0; rf < 4; ++rf)
#pragma unroll
            for (int cf = 0; cf < 4; ++cf) {
                acc[rf][cf] = __builtin_amdgcn_mfma_f32_16x16x32_bf16(af[rf][0], bfr[cf][0], acc[rf][cf], 0, 0, 0);
                acc[rf][cf] = __builtin_amdgcn_mfma_f32_16x16x32_bf16(af[rf][1], bfr[cf][1], acc[rf][cf], 0, 0, 0);
            }
        __builtin_amdgcn_s_setprio(0);
    }
}

// out[r][c] = relu( Sx@Wl^T + h@Wr^T + Sa@Wle^T + bl + [hasdeg]*wlbe )
// 128x128 tile, 4 waves, 32KB LDS, bijective XCD swizzle (rb-pair L2 reuse).
__global__ __launch_bounds__(256, 4) void k_gemm(
    const u16* __restrict__ Sx, const u16* __restrict__ Hb, const u16* __restrict__ Sa,
    const u16* __restrict__ Wlb, const u16* __restrict__ Wrb, const u16* __restrict__ Wleb,
    const float* __restrict__ bl, const float* __restrict__ wlbe,
    const unsigned char* __restrict__ hasdeg,
    u16* hb_out, float* f_out, int M)
{
    __shared__ __align__(16) u16 Alds[128 * 64];
    __shared__ __align__(16) u16 Blds[128 * 64];
    const int tid = threadIdx.x;
    const int lane = tid & 63;
    const int w = tid >> 6;
    const int wr = w & 1, wc = w >> 1;
    const int r16 = lane & 15;
    const int hi = lane >> 4;

    // bijective XCD swizzle (nwg % 8 != 0 safe)
    const int nwg = (int)gridDim.x;
    const int q = nwg >> 3, r = nwg & 7;
    const int xcd = blockIdx.x & 7;
    const int idx = blockIdx.x >> 3;
    const int wgid = (xcd < r ? xcd * (q + 1) : r * (q + 1) + (xcd - r) * q) + idx;

    const int rb = wgid >> 1;
    const int cb = wgid & 1;
    const int r0 = rb * 128;
    const int c0 = cb * 128;

    const f32x4 fzero = {0.f, 0.f, 0.f, 0.f};
    f32x4 acc[4][4];
#pragma unroll
    for (int a = 0; a < 4; ++a)
#pragma unroll
        for (int b = 0; b < 4; ++b) acc[a][b] = fzero;

    do_seg(Sx, Wlb, 256, 256, r0, c0, M, Alds, Blds, lane, w, wr, wc, r16, acc);
    do_seg(Hb, Wrb, 256, 256, r0, c0, M, Alds, Blds, lane, w, wr, wc, r16, acc);
    do_seg(Sa, Wleb, 64, 64, r0, c0, M, Alds, Blds, lane, w, wr, wc, r16, acc);

    // epilogue: C/D map col=lane&15, row=4*(lane>>4)+reg
    float blv[4], wbev[4];
#pragma unroll
    for (int cf = 0; cf < 4; ++cf) {
        int col = c0 + wc * 64 + 16 * cf + r16;
        blv[cf] = bl[col];
        wbev[cf] = wlbe[col];
    }
#pragma unroll
    for (int rf = 0; rf < 4; ++rf)
#pragma unroll
        for (int j = 0; j < 4; ++j) {
            int rr = r0 + wr * 64 + 16 * rf + 4 * hi + j;
            if (rr < M) {
                float hd = hasdeg[rr] ? 1.f : 0.f;
#pragma unroll
                for (int cf = 0; cf < 4; ++cf) {
                    int col = c0 + wc * 64 + 16 * cf + r16;
                    float v = acc[rf][cf][j] + blv[cf] + hd * wbev[cf];
                    v = fmaxf(v, 0.f);
                    if (f_out) f_out[(size_t)rr * 256 + col] = v;
                    if (hb_out) hb_out[(size_t)rr * 256 + col] = f2bf(v);
                }
            }
        }
}

extern "C" void kernel_launch(void* const* d_in, const int* in_sizes, int n_in,
                              void* d_out, int out_size, void* d_ws, size_t ws_size,
                              hipStream_t stream) {
    const float* x    = (const float*)d_in[0];
    const float* attr = (const float*)d_in[1];
    const int*   ei   = (const int*)d_in[2];
    const float* Wl   = (const float*)d_in[3];
    const float* bl   = (const float*)d_in[4];
    const float* Wr   = (const float*)d_in[5];
    const float* We   = (const float*)d_in[6];
    const float* be   = (const float*)d_in[7];
    float* out = (float*)d_out;

    const int N = in_sizes[0] / 256;
    const int E = in_sizes[1] / 64;
    const int* srcA = ei;
    const int* dstA = ei + E;

    char* p = (char*)d_ws;
    auto carve = [&](size_t bytes) -> char* {
        char* q = p;
        p += (bytes + 255) & ~(size_t)255;
        return q;
    };
    u16* hb0    = (u16*)carve((size_t)N * 256 * 2);
    u16* hb1    = (u16*)carve((size_t)N * 256 * 2);
    u16* SxB    = (u16*)carve((size_t)N * 256 * 2);
    u16* SaB    = (u16*)carve((size_t)N * 64 * 2);
    u16* Wlb    = (u16*)carve((size_t)3 * 65536 * 2);
    u16* Wrb    = (u16*)carve((size_t)3 * 65536 * 2);
    u16* Wleb   = (u16*)carve((size_t)3 * 16384 * 2);
    float* wlbe = (float*)carve((size_t)3 * 256 * 4);
    int* deg    = (int*)carve((size_t)N * 4);
    int* rp     = (int*)carve((size_t)(N + 1) * 4);
    int* cur    = (int*)carve((size_t)N * 4);
    int* eid    = (int*)carve((size_t)E * 4);
    int* srcs   = (int*)carve((size_t)E * 4);
    int* part   = (int*)carve((size_t)256 * 4);
    int* bases  = (int*)carve((size_t)256 * 4);
    unsigned char* hasdeg = (unsigned char*)carve((size_t)N);

    const int n4 = (N + 3) / 4;
    k_zero<<<(n4 + 255) / 256, 256, 0, stream>>>((int4*)deg, n4);

    int t4 = N * 64;  // float4 count for x
    k_convcnt<<<(t4 + 255) / 256, 256, 0, stream>>>(x, hb0, t4, dstA, deg, E);
    const int PB = (N + 255) / 256;  // 196 <= 256
    k_part<<<PB, 256, 0, stream>>>(deg, part, N);
    k_scanp<<<1, 256, 0, stream>>>(part, bases, PB);
    k_apply<<<PB, 256, 0, stream>>>(deg, bases, rp, cur, N, E);
    k_fill<<<(E + 255) / 256, 256, 0, stream>>>(dstA, srcA, cur, eid, srcs, E);
    k_sa<<<(N + 3) / 4, 256, 0, stream>>>(attr, rp, eid, SaB, hasdeg, N);
    k_wprep<<<(3 * 65536 + 255) / 256, 256, 0, stream>>>(Wl, Wr, We, be, Wlb, Wrb, Wleb, wlbe);

    const int RB = (N + 127) / 128;
    const int gblocks = RB * 2;   // 2 column-blocks of 128
    u16* hcur = hb0;
    u16* hnxt = hb1;
    for (int l = 0; l < 3; ++l) {
        k_sx<<<(N + 3) / 4, 256, 0, stream>>>(hcur, rp, srcs, SxB, N);
        k_gemm<<<gblocks, 256, 0, stream>>>(SxB, hcur, SaB,
            Wlb + l * 65536, Wrb + l * 65536, Wleb + l * 16384,
            bl + l * 256, wlbe + l * 256, hasdeg,
            (l < 2) ? hnxt : (u16*)nullptr, (l == 2) ? out : (float*)nullptr, N);
        u16* t = hcur; hcur = hnxt; hnxt = t;
    }
}

// Round 15
// 305.765 us; speedup vs baseline: 1.3561x; 1.3561x over previous
//
#include <hip/hip_runtime.h>

typedef __attribute__((ext_vector_type(8))) short bf16x8;
typedef __attribute__((ext_vector_type(4))) float f32x4;
typedef unsigned short u16;

#define AS1 __attribute__((address_space(1)))
#define AS3 __attribute__((address_space(3)))

__device__ __forceinline__ u16 f2bf(float f) {
    union { float f; unsigned u; } v; v.f = f;
    unsigned u = v.u;
    return (u16)((u + 0x7FFFu + ((u >> 16) & 1u)) >> 16);
}
__device__ __forceinline__ float bf2f(u16 h) {
    union { unsigned u; float f; } v; v.u = ((unsigned)h) << 16;
    return v.f;
}

// ---- zero deg
__global__ __launch_bounds__(256) void k_zero(int4* __restrict__ p, int n4) {
    int i = blockIdx.x * 256 + threadIdx.x;
    if (i < n4) p[i] = make_int4(0, 0, 0, 0);
}

// ---- fused fp32->bf16 convert (x -> hb) + degree count
__global__ __launch_bounds__(256) void k_convcnt(const float* __restrict__ x,
                                                 u16* __restrict__ hb, int total4,
                                                 const int* __restrict__ dst,
                                                 int* __restrict__ deg, int E) {
    int i = blockIdx.x * 256 + threadIdx.x;
    if (i < total4) {
        float4 v = ((const float4*)x)[i];
        ushort4 o;
        o.x = f2bf(v.x); o.y = f2bf(v.y); o.z = f2bf(v.z); o.w = f2bf(v.w);
        ((ushort4*)hb)[i] = o;
    }
    if (i < E) atomicAdd(&deg[dst[i]], 1);
}

// ---- hierarchical exclusive scan of deg -> rp, cur ----
__global__ __launch_bounds__(256) void k_part(const int* __restrict__ deg,
                                              int* __restrict__ part, int N) {
    __shared__ int ws[4];
    int i = blockIdx.x * 256 + threadIdx.x;
    int v = (i < N) ? deg[i] : 0;
#pragma unroll
    for (int o = 32; o; o >>= 1) v += __shfl_down(v, o);
    int lane = threadIdx.x & 63, w = threadIdx.x >> 6;
    if (lane == 0) ws[w] = v;
    __syncthreads();
    if (threadIdx.x == 0) part[blockIdx.x] = ws[0] + ws[1] + ws[2] + ws[3];
}

__global__ __launch_bounds__(256) void k_scanp(const int* __restrict__ part,
                                               int* __restrict__ bases, int P) {
    __shared__ int s[256];
    int t = threadIdx.x;
    int v = (t < P) ? part[t] : 0;
    s[t] = v;
    __syncthreads();
#pragma unroll
    for (int o = 1; o < 256; o <<= 1) {
        int u = (t >= o) ? s[t - o] : 0;
        __syncthreads();
        s[t] += u;
        __syncthreads();
    }
    bases[t] = s[t] - v;  // exclusive
}

__global__ __launch_bounds__(256) void k_apply(const int* __restrict__ deg,
                                               const int* __restrict__ bases,
                                               int* __restrict__ rp, int* __restrict__ cur,
                                               int N, int E) {
    __shared__ int s[256];
    int b = blockIdx.x, t = threadIdx.x;
    int i = b * 256 + t;
    int d = (i < N) ? deg[i] : 0;
    s[t] = d;
    __syncthreads();
#pragma unroll
    for (int o = 1; o < 256; o <<= 1) {
        int u = (t >= o) ? s[t - o] : 0;
        __syncthreads();
        s[t] += u;
        __syncthreads();
    }
    if (i < N) {
        int r = bases[b] + s[t] - d;
        rp[i] = r;
        cur[i] = r;
    }
    if (b == (int)gridDim.x - 1 && t == 255) rp[N] = E;
}

__global__ __launch_bounds__(256) void k_fill(const int* __restrict__ dst, const int* __restrict__ src,
                                              int* __restrict__ cur,
                                              int* __restrict__ eid, int* __restrict__ srcs, int E) {
    int e = blockIdx.x * 256 + threadIdx.x;
    if (e < E) {
        int p = atomicAdd(&cur[dst[e]], 1);
        eid[p] = e;
        srcs[p] = src[e];
    }
}

// Sa[v][k] = inv_deg * sum_{e->v} attr[e][k]  (bf16), hasdeg[v]
// 16 lanes x float4 per row; uniform clamp+mask loop (no serial remainder).
__global__ __launch_bounds__(256) void k_sa(const float* __restrict__ attr, const int* __restrict__ rp,
                                            const int* __restrict__ eid, u16* __restrict__ Sa,
                                            unsigned char* __restrict__ hasdeg, int N) {
    int v = blockIdx.x * 4 + (threadIdx.x >> 6);
    if (v >= N) return;
    int l = threadIdx.x & 63;
    int g = l >> 4;          // edge subgroup 0..3
    int c = (l & 15) * 4;    // col base
    int j0 = rp[v], j1 = rp[v + 1];
    float4 a = {0.f, 0.f, 0.f, 0.f};
    int jc = j1 - 1;
    for (int j = j0; j < j1; j += 8) {
        int i0 = j + g;
        int i1 = j + 4 + g;
        float m0 = (i0 < j1) ? 1.f : 0.f;
        float m1 = (i1 < j1) ? 1.f : 0.f;
        int e0 = eid[i0 < jc ? i0 : jc];
        int e1 = eid[i1 < jc ? i1 : jc];
        float4 x0 = *(const float4*)&attr[(size_t)e0 * 64 + c];
        float4 x1 = *(const float4*)&attr[(size_t)e1 * 64 + c];
        a.x += m0 * x0.x + m1 * x1.x;
        a.y += m0 * x0.y + m1 * x1.y;
        a.z += m0 * x0.z + m1 * x1.z;
        a.w += m0 * x0.w + m1 * x1.w;
    }
    a.x += __shfl_xor(a.x, 16); a.y += __shfl_xor(a.y, 16);
    a.z += __shfl_xor(a.z, 16); a.w += __shfl_xor(a.w, 16);
    a.x += __shfl_xor(a.x, 32); a.y += __shfl_xor(a.y, 32);
    a.z += __shfl_xor(a.z, 32); a.w += __shfl_xor(a.w, 32);
    int dg = j1 - j0;
    float m = 1.f / (float)(dg > 1 ? dg : 1);
    if (l < 16) {
        ushort4 o;
        o.x = f2bf(a.x * m); o.y = f2bf(a.y * m);
        o.z = f2bf(a.z * m); o.w = f2bf(a.w * m);
        *(ushort4*)&Sa[(size_t)v * 64 + c] = o;
        if (l == 0) hasdeg[v] = (dg > 0) ? 1 : 0;
    }
}

// Sx[v][:] = inv_deg * sum_{e->v} h[src_e][:]  (bf16 in, fp32 accum, bf16 out)
// 32 lanes x bf16x8 per row; uniform clamp+mask loop (no serial remainder).
__global__ __launch_bounds__(256) void k_sx(const u16* __restrict__ hb, const int* __restrict__ rp,
                                            const int* __restrict__ srcs,
                                            u16* __restrict__ Sx, int N) {
    int v = blockIdx.x * 4 + (threadIdx.x >> 6);
    if (v >= N) return;
    int l = threadIdx.x & 63;
    int h = l >> 5;           // row subgroup 0/1
    int c = (l & 31) * 8;     // col base (bf16)
    int j0 = rp[v], j1 = rp[v + 1];
    float a[8] = {0.f, 0.f, 0.f, 0.f, 0.f, 0.f, 0.f, 0.f};
    int jc = j1 - 1;
    for (int j = j0; j < j1; j += 8) {
        int i0 = j + h;
        int i1 = j + 2 + h;
        int i2 = j + 4 + h;
        int i3 = j + 6 + h;
        float m0 = (i0 < j1) ? 1.f : 0.f;
        float m1 = (i1 < j1) ? 1.f : 0.f;
        float m2 = (i2 < j1) ? 1.f : 0.f;
        float m3 = (i3 < j1) ? 1.f : 0.f;
        int s0 = srcs[i0 < jc ? i0 : jc];
        int s1 = srcs[i1 < jc ? i1 : jc];
        int s2 = srcs[i2 < jc ? i2 : jc];
        int s3 = srcs[i3 < jc ? i3 : jc];
        bf16x8 u0 = *(const bf16x8*)&hb[(size_t)s0 * 256 + c];
        bf16x8 u1 = *(const bf16x8*)&hb[(size_t)s1 * 256 + c];
        bf16x8 u2 = *(const bf16x8*)&hb[(size_t)s2 * 256 + c];
        bf16x8 u3 = *(const bf16x8*)&hb[(size_t)s3 * 256 + c];
#pragma unroll
        for (int i = 0; i < 8; ++i)
            a[i] += (m0 * bf2f((u16)u0[i]) + m1 * bf2f((u16)u1[i]))
                  + (m2 * bf2f((u16)u2[i]) + m3 * bf2f((u16)u3[i]));
    }
#pragma unroll
    for (int i = 0; i < 8; ++i) a[i] += __shfl_xor(a[i], 32);
    int dg = j1 - j0;
    float m = 1.f / (float)(dg > 1 ? dg : 1);
    if (l < 32) {
        bf16x8 o;
#pragma unroll
        for (int i = 0; i < 8; ++i) o[i] = (short)f2bf(a[i] * m);
        *(bf16x8*)&Sx[(size_t)v * 256 + c] = o;
    }
}

// fused weight prep: Wl/Wr -> bf16; Wle = Wl@We -> bf16; wlbe = Wl@be
__global__ __launch_bounds__(256) void k_wprep(const float* __restrict__ Wl, const float* __restrict__ Wr,
                                               const float* __restrict__ We, const float* __restrict__ be,
                                               u16* __restrict__ Wlb, u16* __restrict__ Wrb,
                                               u16* __restrict__ Wleb, float* __restrict__ wlbe) {
    int t = blockIdx.x * 256 + threadIdx.x;
    if (t < 3 * 65536) { Wlb[t] = f2bf(Wl[t]); Wrb[t] = f2bf(Wr[t]); }
    if (t < 3 * 16384) {
        int l = t >> 14;
        int r = t & 16383;
        int d = r >> 6, jj = r & 63;
        const float* wl = Wl + ((size_t)l << 16) + (size_t)d * 256;
        const float* we = We + ((size_t)l << 14) + jj;
        float s = 0.f;
        for (int p = 0; p < 256; ++p) s += wl[p] * we[(size_t)p * 64];
        Wleb[t] = f2bf(s);
    }
    if (t < 768) {
        int l = t >> 8, d = t & 255;
        const float* wl = Wl + ((size_t)l << 16) + (size_t)d * 256;
        const float* b = be + l * 256;
        float s = 0.f;
        for (int p = 0; p < 256; ++p) s += wl[p] * b[p];
        wlbe[t] = s;
    }
}

// ---- m97-template GEMM segment: 128x128 tile, BK=64, global_load_lds staging.
// Linear LDS layout (R14's source-swizzle broke global coalescing: FETCH 31->80MB,
// WRITE 29->152MB, -68% perf. Bank conflicts are hidden by the stage-drain path.)
__device__ __forceinline__ void do_seg(const u16* __restrict__ A, const u16* __restrict__ B,
                                       int lda, int K, int r0, int c0, int M,
                                       u16* Alds, u16* Blds,
                                       int lane, int w, int wr, int wc,
                                       int r16, int kq, f32x4 (&acc)[4][4]) {
    const int rloc = lane >> 3;        // 0..7 row within 8-row chunk
    const int cE = (lane & 7) * 8;     // element col within 64-wide k-slice
    for (int k0 = 0; k0 < K; k0 += 64) {
        __syncthreads();   // protect LDS from previous k-step's readers
#pragma unroll
        for (int i = 0; i < 4; ++i) {
            int ch = w * 4 + i;                       // chunk 0..15 (8 rows each)
            int ar = r0 + ch * 8 + rloc;
            ar = ar < M ? ar : M - 1;                 // clamp (dup rows, masked at store)
            __builtin_amdgcn_global_load_lds(
                (const AS1 void*)(A + (size_t)ar * lda + k0 + cE),
                (AS3 void*)(Alds + ch * 512), 16, 0, 0);
            int br = c0 + ch * 8 + rloc;
            __builtin_amdgcn_global_load_lds(
                (const AS1 void*)(B + (size_t)br * K + k0 + cE),
                (AS3 void*)(Blds + ch * 512), 16, 0, 0);
        }
        __syncthreads();   // staged data visible
        bf16x8 af[4][2], bfr[4][2];
#pragma unroll
        for (int rf = 0; rf < 4; ++rf) {
            af[rf][0] = *(const bf16x8*)&Alds[(wr * 64 + rf * 16 + r16) * 64 + kq];
            af[rf][1] = *(const bf16x8*)&Alds[(wr * 64 + rf * 16 + r16) * 64 + 32 + kq];
        }
#pragma unroll
        for (int cf = 0; cf < 4; ++cf) {
            bfr[cf][0] = *(const bf16x8*)&Blds[(wc * 64 + cf * 16 + r16) * 64 + kq];
            bfr[cf][1] = *(const bf16x8*)&Blds[(wc * 64 + cf * 16 + r16) * 64 + 32 + kq];
        }
#pragma unroll
        for (int rf = 0; rf < 4; ++rf)
#pragma unroll
            for (int cf = 0; cf < 4; ++cf) {
                acc[rf][cf] = __builtin_amdgcn_mfma_f32_16x16x32_bf16(af[rf][0], bfr[cf][0], acc[rf][cf], 0, 0, 0);
                acc[rf][cf] = __builtin_amdgcn_mfma_f32_16x16x32_bf16(af[rf][1], bfr[cf][1], acc[rf][cf], 0, 0, 0);
            }
    }
}

// out[r][c] = relu( Sx@Wl^T + h@Wr^T + Sa@Wle^T + bl + [hasdeg]*wlbe )
// 128x128 tile, 4 waves, 32KB LDS. Bijective XCD swizzle (m204): both
// column-halves of an rb-pair land on the SAME XCD back-to-back -> the
// second read of each A-row hits XCD-local L2 instead of HBM.
__global__ __launch_bounds__(256, 4) void k_gemm(
    const u16* __restrict__ Sx, const u16* __restrict__ Hb, const u16* __restrict__ Sa,
    const u16* __restrict__ Wlb, const u16* __restrict__ Wrb, const u16* __restrict__ Wleb,
    const float* __restrict__ bl, const float* __restrict__ wlbe,
    const unsigned char* __restrict__ hasdeg,
    u16* hb_out, float* f_out, int M)
{
    __shared__ __align__(16) u16 Alds[128 * 64];
    __shared__ __align__(16) u16 Blds[128 * 64];
    const int tid = threadIdx.x;
    const int lane = tid & 63;
    const int w = tid >> 6;
    const int wr = w & 1, wc = w >> 1;
    const int r16 = lane & 15;
    const int hi = lane >> 4;
    const int kq = hi * 8;

    // bijective XCD swizzle (nwg % 8 != 0 safe): orig%8 = xcd -> contiguous chunk
    const int nwg = (int)gridDim.x;
    const int q = nwg >> 3, r = nwg & 7;
    const int xcd = blockIdx.x & 7;
    const int idx = blockIdx.x >> 3;
    const int wgid = (xcd < r ? xcd * (q + 1) : r * (q + 1) + (xcd - r) * q) + idx;

    const int rb = wgid >> 1;
    const int cb = wgid & 1;
    const int r0 = rb * 128;
    const int c0 = cb * 128;

    const f32x4 fzero = {0.f, 0.f, 0.f, 0.f};
    f32x4 acc[4][4];
#pragma unroll
    for (int a = 0; a < 4; ++a)
#pragma unroll
        for (int b = 0; b < 4; ++b) acc[a][b] = fzero;

    do_seg(Sx, Wlb, 256, 256, r0, c0, M, Alds, Blds, lane, w, wr, wc, r16, kq, acc);
    do_seg(Hb, Wrb, 256, 256, r0, c0, M, Alds, Blds, lane, w, wr, wc, r16, kq, acc);
    do_seg(Sa, Wleb, 64, 64, r0, c0, M, Alds, Blds, lane, w, wr, wc, r16, kq, acc);

    // epilogue: C/D map col=lane&15, row=4*(lane>>4)+reg
    float blv[4], wbev[4];
#pragma unroll
    for (int cf = 0; cf < 4; ++cf) {
        int col = c0 + wc * 64 + 16 * cf + r16;
        blv[cf] = bl[col];
        wbev[cf] = wlbe[col];
    }
#pragma unroll
    for (int rf = 0; rf < 4; ++rf)
#pragma unroll
        for (int j = 0; j < 4; ++j) {
            int rr = r0 + wr * 64 + 16 * rf + 4 * hi + j;
            if (rr < M) {
                float hd = hasdeg[rr] ? 1.f : 0.f;
#pragma unroll
                for (int cf = 0; cf < 4; ++cf) {
                    int col = c0 + wc * 64 + 16 * cf + r16;
                    float v = acc[rf][cf][j] + blv[cf] + hd * wbev[cf];
                    v = fmaxf(v, 0.f);
                    if (f_out) f_out[(size_t)rr * 256 + col] = v;
                    if (hb_out) hb_out[(size_t)rr * 256 + col] = f2bf(v);
                }
            }
        }
}

extern "C" void kernel_launch(void* const* d_in, const int* in_sizes, int n_in,
                              void* d_out, int out_size, void* d_ws, size_t ws_size,
                              hipStream_t stream) {
    const float* x    = (const float*)d_in[0];
    const float* attr = (const float*)d_in[1];
    const int*   ei   = (const int*)d_in[2];
    const float* Wl   = (const float*)d_in[3];
    const float* bl   = (const float*)d_in[4];
    const float* Wr   = (const float*)d_in[5];
    const float* We   = (const float*)d_in[6];
    const float* be   = (const float*)d_in[7];
    float* out = (float*)d_out;

    const int N = in_sizes[0] / 256;
    const int E = in_sizes[1] / 64;
    const int* srcA = ei;
    const int* dstA = ei + E;

    char* p = (char*)d_ws;
    auto carve = [&](size_t bytes) -> char* {
        char* q = p;
        p += (bytes + 255) & ~(size_t)255;
        return q;
    };
    u16* hb0    = (u16*)carve((size_t)N * 256 * 2);
    u16* hb1    = (u16*)carve((size_t)N * 256 * 2);
    u16* SxB    = (u16*)carve((size_t)N * 256 * 2);
    u16* SaB    = (u16*)carve((size_t)N * 64 * 2);
    u16* Wlb    = (u16*)carve((size_t)3 * 65536 * 2);
    u16* Wrb    = (u16*)carve((size_t)3 * 65536 * 2);
    u16* Wleb   = (u16*)carve((size_t)3 * 16384 * 2);
    float* wlbe = (float*)carve((size_t)3 * 256 * 4);
    int* deg    = (int*)carve((size_t)N * 4);
    int* rp     = (int*)carve((size_t)(N + 1) * 4);
    int* cur    = (int*)carve((size_t)N * 4);
    int* eid    = (int*)carve((size_t)E * 4);
    int* srcs   = (int*)carve((size_t)E * 4);
    int* part   = (int*)carve((size_t)256 * 4);
    int* bases  = (int*)carve((size_t)256 * 4);
    unsigned char* hasdeg = (unsigned char*)carve((size_t)N);

    const int n4 = (N + 3) / 4;   // deg carved 256B-aligned; int4 stores safe
    k_zero<<<(n4 + 255) / 256, 256, 0, stream>>>((int4*)deg, n4);

    int t4 = N * 64;  // float4 count for x
    k_convcnt<<<(t4 + 255) / 256, 256, 0, stream>>>(x, hb0, t4, dstA, deg, E);
    const int PB = (N + 255) / 256;  // 196 <= 256
    k_part<<<PB, 256, 0, stream>>>(deg, part, N);
    k_scanp<<<1, 256, 0, stream>>>(part, bases, PB);
    k_apply<<<PB, 256, 0, stream>>>(deg, bases, rp, cur, N, E);
    k_fill<<<(E + 255) / 256, 256, 0, stream>>>(dstA, srcA, cur, eid, srcs, E);
    k_sa<<<(N + 3) / 4, 256, 0, stream>>>(attr, rp, eid, SaB, hasdeg, N);
    k_wprep<<<(3 * 65536 + 255) / 256, 256, 0, stream>>>(Wl, Wr, We, be, Wlb, Wrb, Wleb, wlbe);

    const int RB = (N + 127) / 128;
    const int gblocks = RB * 2;   // 2 column-blocks of 128
    u16* hcur = hb0;
    u16* hnxt = hb1;
    for (int l = 0; l < 3; ++l) {
        k_sx<<<(N + 3) / 4, 256, 0, stream>>>(hcur, rp, srcs, SxB, N);
        k_gemm<<<gblocks, 256, 0, stream>>>(SxB, hcur, SaB,
            Wlb + l * 65536, Wrb + l * 65536, Wleb + l * 16384,
            bl + l * 256, wlbe + l * 256, hasdeg,
            (l < 2) ? hnxt : (u16*)nullptr, (l == 2) ? out : (float*)nullptr, N);
        u16* t = hcur; hcur = hnxt; hnxt = t;
    }
}